// Round 14
// baseline (250.665 us; speedup 1.0000x reference)
//
#include <hip/hip_runtime.h>
#include <hip/hip_bf16.h>

typedef __attribute__((ext_vector_type(8))) __bf16 bf16x8;
typedef __attribute__((ext_vector_type(4))) float f32x4;
typedef unsigned short ushort_t;
typedef unsigned int uint_t;

#define CCH 256
#define BB 4

// kc-plane strides in shorts: level npix * 32 ch
#define NP32_0 3145728   // 4*128*192*32
#define NP32_1 786432    // 4*64*96*32
#define NP32_2 196608    // 4*32*48*32
#define NP32_3 49152     // 4*16*24*32

#define NPX0 98304
#define NPX1 24576
#define NPX2 6144
#define NPX3 1536
#define NPXT (NPX0 + NPX1 + NPX2 + NPX3)   // 130560

__device__ __forceinline__ ushort_t f2b(float v) {
    __hip_bfloat16 h = __float2bfloat16(v);
    return *reinterpret_cast<ushort_t*>(&h);
}

__device__ __forceinline__ void gload16(const void* g, void* l) {
    __builtin_amdgcn_global_load_lds(
        (const __attribute__((address_space(1))) void*)g,
        (__attribute__((address_space(3))) void*)l, 16, 0, 0);
}

struct PrepOut {
    ushort_t* o0; ushort_t* o1; ushort_t* o2; ushort_t* o3;
    float* s0; float* s1; float* s2; float* s3;     // partial ssq [8][npx]
    float* n0; float* n1; float* n2; float* n3;     // invnorms
};

// =====================================================================
// prep_stream v4: r13 per-thread algorithm, repacked 4 waves/block where
// all 4 waves share ONE kc plane and cover 4 CONTIGUOUS spatial stripes
// (ys = ysq*4 + wave). Single read stream per block -> page/L3 local,
// unlike r12's 4-kc-plane packing (which doubled FETCH). Only the
// block/wave decode differs from r13.
// =====================================================================
__global__ __launch_bounds__(256) void prep_stream_kernel(
    const float* __restrict__ fa, const float* __restrict__ fb,
    PrepOut Pa, PrepOut Pb)
{
    const int H = 128, W = 192, HW = H * W;
    const float* fin = blockIdx.y ? fb : fa;
    PrepOut P = blockIdx.y ? Pb : Pa;

    int wv = threadIdx.x >> 6;
    int bid = blockIdx.x;
    int kc = bid & 7;
    int r0i = bid >> 3;          // 0..95 = 12 xc * 2 ysq * 4 b
    int xc = r0i % 12;
    int ysq = (r0i / 12) % 2;
    int b  = r0i / 24;
    int ys = ysq * 4 + wv;       // wave covers one 16-row stripe

    int t = threadIdx.x & 63;
    int ty = t >> 3, tx = t & 7;
    int row0 = ys * 16 + 2 * ty;
    int col0 = xc * 16 + 2 * tx;

    const float* base = fin + (size_t)(b * 256 + kc * 32) * HW + (size_t)row0 * W + col0;

    uint_t uu0[4][16];
    uint_t uu1[16], uu2[16], uu3[16];
    float ssqA = 0.f, ssqB = 0.f, ssqC = 0.f, ssqD = 0.f;
    float ssq1 = 0.f, ssq2 = 0.f, ssq3 = 0.f;

    bool own2 = ((tx & 1) | (ty & 1)) == 0;
    bool own3 = ((tx & 3) | (ty & 3)) == 0;

    // ---- depth-4 prefetch ring (static indices via full unroll) ----
    float2 sra[4], srb[4];
    #pragma unroll
    for (int i = 0; i < 4; ++i) {
        sra[i] = *reinterpret_cast<const float2*>(base + (size_t)i * HW);
        srb[i] = *reinterpret_cast<const float2*>(base + (size_t)i * HW + W);
    }

    #pragma unroll
    for (int cc = 0; cc < 32; ++cc) {
        float2 ra = sra[cc & 3];
        float2 rb = srb[cc & 3];
        if (cc + 4 < 32) {
            sra[cc & 3] = *reinterpret_cast<const float2*>(base + (size_t)(cc + 4) * HW);
            srb[cc & 3] = *reinterpret_cast<const float2*>(base + (size_t)(cc + 4) * HW + W);
        }

        ssqA = fmaf(ra.x, ra.x, ssqA);
        ssqB = fmaf(ra.y, ra.y, ssqB);
        ssqC = fmaf(rb.x, rb.x, ssqC);
        ssqD = fmaf(rb.y, rb.y, ssqD);

        ushort_t b00 = f2b(ra.x), b01 = f2b(ra.y), b10 = f2b(rb.x), b11 = f2b(rb.y);
        if ((cc & 1) == 0) {
            uu0[0][cc >> 1] = (uint_t)b00;
            uu0[1][cc >> 1] = (uint_t)b01;
            uu0[2][cc >> 1] = (uint_t)b10;
            uu0[3][cc >> 1] = (uint_t)b11;
        } else {
            uu0[0][cc >> 1] |= ((uint_t)b00) << 16;
            uu0[1][cc >> 1] |= ((uint_t)b01) << 16;
            uu0[2][cc >> 1] |= ((uint_t)b10) << 16;
            uu0[3][cc >> 1] |= ((uint_t)b11) << 16;
        }

        float l1 = 0.25f * (ra.x + ra.y + rb.x + rb.y);
        ssq1 = fmaf(l1, l1, ssq1);
        if ((cc & 1) == 0) uu1[cc >> 1] = (uint_t)f2b(l1);
        else               uu1[cc >> 1] |= ((uint_t)f2b(l1)) << 16;

        float sa = l1 + __shfl_xor(l1, 1);
        float l2 = 0.25f * (sa + __shfl_xor(sa, 8));
        float sb = l2 + __shfl_xor(l2, 2);
        float l3 = 0.25f * (sb + __shfl_xor(sb, 16));

        if (own2) ssq2 = fmaf(l2, l2, ssq2);
        if (own3) ssq3 = fmaf(l3, l3, ssq3);
        if ((cc & 1) == 0) { uu2[cc >> 1] = (uint_t)f2b(l2); uu3[cc >> 1] = (uint_t)f2b(l3); }
        else               { uu2[cc >> 1] |= ((uint_t)f2b(l2)) << 16; uu3[cc >> 1] |= ((uint_t)f2b(l3)) << 16; }
    }

    // ---- L0 stores: 4 pixels x 64B ----
    float sqv[4] = { ssqA, ssqB, ssqC, ssqD };
    #pragma unroll
    for (int r = 0; r < 2; ++r)
        #pragma unroll
        for (int cx = 0; cx < 2; ++cx) {
            int pxi = r * 2 + cx;
            size_t px = (size_t)(b * H + row0 + r) * W + col0 + cx;
            ushort_t* dst = P.o0 + (size_t)kc * NP32_0 + px * 32;
            *reinterpret_cast<uint4*>(dst +  0) = make_uint4(uu0[pxi][0],  uu0[pxi][1],  uu0[pxi][2],  uu0[pxi][3]);
            *reinterpret_cast<uint4*>(dst +  8) = make_uint4(uu0[pxi][4],  uu0[pxi][5],  uu0[pxi][6],  uu0[pxi][7]);
            *reinterpret_cast<uint4*>(dst + 16) = make_uint4(uu0[pxi][8],  uu0[pxi][9],  uu0[pxi][10], uu0[pxi][11]);
            *reinterpret_cast<uint4*>(dst + 24) = make_uint4(uu0[pxi][12], uu0[pxi][13], uu0[pxi][14], uu0[pxi][15]);
            P.s0[(size_t)kc * NPX0 + px] = sqv[pxi];
        }

    // ---- L1 store ----
    size_t l1px = (size_t)(b * 64 + ys * 8 + ty) * 96 + xc * 8 + tx;
    {
        ushort_t* dst = P.o1 + (size_t)kc * NP32_1 + l1px * 32;
        *reinterpret_cast<uint4*>(dst +  0) = make_uint4(uu1[0],  uu1[1],  uu1[2],  uu1[3]);
        *reinterpret_cast<uint4*>(dst +  8) = make_uint4(uu1[4],  uu1[5],  uu1[6],  uu1[7]);
        *reinterpret_cast<uint4*>(dst + 16) = make_uint4(uu1[8],  uu1[9],  uu1[10], uu1[11]);
        *reinterpret_cast<uint4*>(dst + 24) = make_uint4(uu1[12], uu1[13], uu1[14], uu1[15]);
        P.s1[(size_t)kc * NPX1 + l1px] = ssq1;
    }

    // ---- L2 store (owner lanes) ----
    if (own2) {
        size_t l2px = (size_t)(b * 32 + ys * 4 + (ty >> 1)) * 48 + xc * 4 + (tx >> 1);
        ushort_t* dst = P.o2 + (size_t)kc * NP32_2 + l2px * 32;
        *reinterpret_cast<uint4*>(dst +  0) = make_uint4(uu2[0],  uu2[1],  uu2[2],  uu2[3]);
        *reinterpret_cast<uint4*>(dst +  8) = make_uint4(uu2[4],  uu2[5],  uu2[6],  uu2[7]);
        *reinterpret_cast<uint4*>(dst + 16) = make_uint4(uu2[8],  uu2[9],  uu2[10], uu2[11]);
        *reinterpret_cast<uint4*>(dst + 24) = make_uint4(uu2[12], uu2[13], uu2[14], uu2[15]);
        P.s2[(size_t)kc * NPX2 + l2px] = ssq2;
    }

    // ---- L3 store (owner lanes) ----
    if (own3) {
        size_t l3px = (size_t)(b * 16 + ys * 2 + (ty >> 2)) * 24 + xc * 2 + (tx >> 2);
        ushort_t* dst = P.o3 + (size_t)kc * NP32_3 + l3px * 32;
        *reinterpret_cast<uint4*>(dst +  0) = make_uint4(uu3[0],  uu3[1],  uu3[2],  uu3[3]);
        *reinterpret_cast<uint4*>(dst +  8) = make_uint4(uu3[4],  uu3[5],  uu3[6],  uu3[7]);
        *reinterpret_cast<uint4*>(dst + 16) = make_uint4(uu3[8],  uu3[9],  uu3[10], uu3[11]);
        *reinterpret_cast<uint4*>(dst + 24) = make_uint4(uu3[12], uu3[13], uu3[14], uu3[15]);
        P.s3[(size_t)kc * NPX3 + l3px] = ssq3;
    }
}

// =====================================================================
// invnorm finalize: sum the 8 kc-partials, write 1/max(sqrt,eps)
// =====================================================================
__global__ __launch_bounds__(256) void invnorm_fin_kernel(PrepOut Pa, PrepOut Pb)
{
    int tid = blockIdx.x * 256 + threadIdx.x;
    if (tid >= 2 * NPXT) return;
    PrepOut P = (tid >= NPXT) ? Pb : Pa;
    int i = (tid >= NPXT) ? (tid - NPXT) : tid;

    const float* s; float* n; int npx, j;
    if (i < NPX0)                       { s = P.s0; n = P.n0; npx = NPX0; j = i; }
    else if (i < NPX0 + NPX1)           { s = P.s1; n = P.n1; npx = NPX1; j = i - NPX0; }
    else if (i < NPX0 + NPX1 + NPX2)    { s = P.s2; n = P.n2; npx = NPX2; j = i - NPX0 - NPX1; }
    else                                { s = P.s3; n = P.n3; npx = NPX3; j = i - NPX0 - NPX1 - NPX2; }

    float sum = 0.f;
    #pragma unroll
    for (int k = 0; k < 8; ++k) sum += s[(size_t)k * npx + j];
    n[j] = 1.f / fmaxf(sqrtf(sum), 1e-12f);
}

// =====================================================================
// corr_fused (unchanged from round 10 — proven)
// =====================================================================
struct CorrLvl {
    const ushort_t* f1n; const ushort_t* f2n;
    const float* in1; const float* in2; const float* dt;
    float* out;
    int H, W, TX, TY, npix32;
};

__global__ __launch_bounds__(256, 2) void corr_fused_kernel(
    CorrLvl Lv0, CorrLvl Lv1, CorrLvl Lv2, const ushort_t* __restrict__ zblk)
{
    __shared__ char smem[65536];
    char* As = smem;
    char* Bs = smem + 16384;

    int bid = blockIdx.x;
    CorrLvl L;
    int local;
    if (bid < 768)      { L = Lv0; local = bid; }
    else if (bid < 960) { L = Lv1; local = bid - 768; }
    else                { L = Lv2; local = bid - 960; }

    int H = L.H, W = L.W, TX = L.TX, TY = L.TY, npix32 = L.npix32;
    int cpx = (BB * TX * TY) >> 3;
    int swz = (local & 7) * cpx + (local >> 3);
    int tx = swz % TX;
    int ty = (swz / TX) % TY;
    int b  = swz / (TX * TY);
    int x0 = tx * 16, y0 = ty * 8;

    int tid = threadIdx.x;
    int w = tid >> 6, lane = tid & 63;
    int kg = lane >> 4, col = lane & 15;
    int r2 = col >> 2, c2 = col & 3;
    int sy = w >> 1, p = w & 1;
    int kgx = kg ^ c2;

    const ushort_t* srcA[2]; char* ldsA[2];
    #pragma unroll
    for (int q = 0; q < 2; ++q) {
        int row = w * 2 + q;
        int px = lane >> 2, js = lane & 3;
        int j = js ^ (px & 3);
        srcA[q] = L.f1n + ((size_t)((b * H + y0 + row) * W) + x0 + px) * 32 + j * 8;
        ldsA[q] = As + row * 1024;
    }
    const ushort_t* srcB[6]; int advB[6]; char* ldsB[6];
    #pragma unroll
    for (int q = 0; q < 6; ++q) {
        int u = (w * 6 + q) * 64 + lane;
        int row = u / 96, rem = u % 96;
        int px = rem >> 2, js = rem & 3;
        int j = js ^ (px & 3);
        int py = y0 - 4 + row, pxg = x0 - 4 + px;
        bool v = (py >= 0) && (py < H) && (pxg >= 0) && (pxg < W);
        srcB[q] = v ? (L.f2n + ((size_t)((b * H + py) * W) + pxg) * 32 + j * 8) : (zblk + j * 8);
        advB[q] = v ? npix32 : 0;
        ldsB[q] = Bs + (w * 6 + q) * 1024;
    }

    int aoff[2], boff[3][4];
    #pragma unroll
    for (int s = 0; s < 2; ++s) {
        int ly = 4 * sy + r2;
        int lx = 4 * (2 * p + s) + c2;
        aoff[s] = ((ly * 16 + lx) * 4 + kgx) * 16;
    }
    #pragma unroll
    for (int i = 0; i < 3; ++i)
        #pragma unroll
        for (int j = 0; j < 4; ++j) {
            int wy = 4 * (sy + i) + r2;
            int wx = 4 * (2 * p + j) + c2;
            boff[i][j] = ((wy * 24 + wx) * 4 + kgx) * 16;
        }

    f32x4 acc0[3][3] = {};
    f32x4 acc1[3][3] = {};

    #pragma unroll
    for (int q = 0; q < 2; ++q) { gload16(srcA[q], ldsA[q]); srcA[q] += npix32; }
    #pragma unroll
    for (int q = 0; q < 6; ++q) { gload16(srcB[q], ldsB[q]); srcB[q] += advB[q]; }

    int buf = 0;
    #pragma unroll 1
    for (int kc = 0; kc < 8; ++kc) {
        if (kc < 7) {
            int boA = (buf ^ 1) * 8192;
            int boB = (buf ^ 1) * 24576;
            #pragma unroll
            for (int q = 0; q < 2; ++q) { gload16(srcA[q], ldsA[q] + boA); srcA[q] += npix32; }
            #pragma unroll
            for (int q = 0; q < 6; ++q) { gload16(srcB[q], ldsB[q] + boB); srcB[q] += advB[q]; }
            __builtin_amdgcn_sched_barrier(0);
            asm volatile("s_waitcnt vmcnt(8)" ::: "memory");
        } else {
            __builtin_amdgcn_sched_barrier(0);
            asm volatile("s_waitcnt vmcnt(0)" ::: "memory");
        }
        __builtin_amdgcn_s_barrier();
        __builtin_amdgcn_sched_barrier(0);

        const char* Ab = As + buf * 8192;
        const char* Bb = Bs + buf * 24576;
        bf16x8 av0 = *(const bf16x8*)(Ab + aoff[0]);
        bf16x8 av1 = *(const bf16x8*)(Ab + aoff[1]);
        #pragma unroll
        for (int i = 0; i < 3; ++i) {
            #pragma unroll
            for (int j = 0; j < 4; ++j) {
                bf16x8 bv = *(const bf16x8*)(Bb + boff[i][j]);
                if (j < 3) acc0[i][j]     = __builtin_amdgcn_mfma_f32_16x16x32_bf16(av0, bv, acc0[i][j], 0, 0, 0);
                if (j > 0) acc1[i][j - 1] = __builtin_amdgcn_mfma_f32_16x16x32_bf16(av1, bv, acc1[i][j - 1], 0, 0, 0);
            }
        }
        if (kc < 7) {
            __builtin_amdgcn_sched_barrier(0);
            __builtin_amdgcn_s_barrier();
            __builtin_amdgcn_sched_barrier(0);
        }
        buf ^= 1;
    }

    float inv1v[2][4], dtv[2][4];
    #pragma unroll
    for (int s = 0; s < 2; ++s) {
        int sxs = 2 * p + s;
        #pragma unroll
        for (int rr = 0; rr < 4; ++rr) {
            int m = kg * 4 + rr;
            int iy = m >> 2, ix = m & 3;
            int pix = (b * H + y0 + 4 * sy + iy) * W + x0 + 4 * sxs + ix;
            inv1v[s][rr] = L.in1[pix];
            dtv[s][rr]   = L.dt[pix];
        }
    }
    #pragma unroll
    for (int s = 0; s < 2; ++s) {
        int sxs = 2 * p + s;
        #pragma unroll
        for (int i = 0; i < 3; ++i) {
            #pragma unroll
            for (int jj = 0; jj < 3; ++jj) {
                int wy = 4 * (sy + i) + r2;
                int wxr = 4 * (sxs + jj) + c2;
                int py = y0 - 4 + wy, px = x0 - 4 + wxr;
                bool v = (py >= 0) && (py < H) && (px >= 0) && (px < W);
                float i2 = v ? L.in2[(b * H + py) * W + px] : 0.f;
                f32x4 a = (s == 0) ? acc0[i][jj] : acc1[i][jj];
                #pragma unroll
                for (int rr = 0; rr < 4; ++rr) {
                    int m = kg * 4 + rr;
                    int iy = m >> 2, ix = m & 3;
                    int oy = iy + 8 - (4 * i + r2);
                    int ox = ix + 8 - (4 * jj + c2);
                    if (oy >= 0 && oy < 9 && ox >= 0 && ox < 9) {
                        int gy = y0 + 4 * sy + iy, gx = x0 + 4 * sxs + ix;
                        L.out[((size_t)(b * 81 + oy * 9 + ox) * H + gy) * W + gx]
                            = a[rr] * inv1v[s][rr] * i2 + dtv[s][rr];
                    }
                }
            }
        }
    }
}

// =====================================================================
// corr_mfma — L3 only (unchanged)
// =====================================================================
__global__ __launch_bounds__(256) void corr_mfma_kernel(
    const ushort_t* __restrict__ f1n, const ushort_t* __restrict__ f2n,
    const float* __restrict__ invn1, const float* __restrict__ invn2,
    const float* __restrict__ dt, float* __restrict__ out,
    int H, int W, int TX, int TY, int zoff)
{
    int wid  = threadIdx.x >> 6;
    int lane = threadIdx.x & 63;
    int tile = blockIdx.x * 4 + wid;
    int ntiles = BB * TY * TX;
    if (tile >= ntiles) return;
    int tx = tile % TX;
    int ty = (tile / TX) % TY;
    int b  = tile / (TX * TY);
    int x0 = tx * 4, y0 = ty * 4;

    int col = lane & 15;
    int kg  = lane >> 4;

    int iyA = col >> 2, ixA = col & 3;
    int a_off = (((b * H + y0 + iyA) * W) + x0 + ixA) * 32 + kg * 8;

    int b_off[9], badv[9];
    uint_t vmask = 0;
    #pragma unroll
    for (int tt = 0; tt < 9; ++tt) {
        int w = tt * 16 + col;
        int wy = w / 12, wx = w % 12;
        int py = y0 + wy - 4, px = x0 + wx - 4;
        bool v = (py >= 0) && (py < H) && (px >= 0) && (px < W);
        b_off[tt] = v ? (((b * H + py) * W + px) * 32 + kg * 8) : (zoff + kg * 8);
        badv[tt] = v ? NP32_3 : 0;
        if (v) vmask |= (1u << tt);
    }

    f32x4 acc[9] = {};
    #pragma unroll
    for (int kb = 0; kb < 8; ++kb) {
        bf16x8 av = *reinterpret_cast<const bf16x8*>(f1n + a_off + kb * NP32_3);
        #pragma unroll
        for (int tt = 0; tt < 9; ++tt) {
            bf16x8 bv = *reinterpret_cast<const bf16x8*>(f2n + b_off[tt]);
            acc[tt] = __builtin_amdgcn_mfma_f32_16x16x32_bf16(av, bv, acc[tt], 0, 0, 0);
            b_off[tt] += badv[tt];
        }
    }

    float inv1[4], dts[4];
    #pragma unroll
    for (int r = 0; r < 4; ++r) {
        int m = kg * 4 + r;
        int iy = m >> 2, ix = m & 3;
        int pix = (b * H + y0 + iy) * W + x0 + ix;
        inv1[r] = invn1[pix];
        dts[r]  = dt[pix];
    }
    #pragma unroll
    for (int tt = 0; tt < 9; ++tt) {
        int w = tt * 16 + col;
        int wy = w / 12, wx = w % 12;
        int py = y0 + wy - 4, px = x0 + wx - 4;
        float i2 = ((vmask >> tt) & 1u) ? invn2[(b * H + py) * W + px] : 0.f;
        #pragma unroll
        for (int r = 0; r < 4; ++r) {
            int m = kg * 4 + r;
            int iy = m >> 2, ix = m & 3;
            int oy = iy + 8 - wy, ox = ix + 8 - wx;
            if (oy >= 0 && oy < 9 && ox >= 0 && ox < 9) {
                int o = oy * 9 + ox;
                out[((size_t)(b * 81 + o) * H + (y0 + iy)) * W + (x0 + ix)]
                    = acc[tt][r] * inv1[r] * i2 + dts[r];
            }
        }
    }
}

// =====================================================================
// depth (unchanged)
// =====================================================================
__global__ __launch_bounds__(256) void depth_kernel(
    const float* __restrict__ d1, const float* __restrict__ d2,
    const float* __restrict__ dw,
    float* __restrict__ dt0, float* __restrict__ dt1,
    float* __restrict__ dt2, float* __restrict__ dt3)
{
    int rid = blockIdx.x * 256 + threadIdx.x;
    if (rid >= 4 * 16 * 24) return;
    int b = rid / 384, rr = rid % 384, ry = rr / 24, rx = rr % 24;
    const int H = 128, W = 192;
    float w0 = dw[0];
    size_t base0 = ((size_t)b * H + ry * 8) * W + rx * 8;

    float q1[4][4], q2[4][4];
    #pragma unroll
    for (int yy = 0; yy < 4; ++yy) {
        float4 a0 = *reinterpret_cast<const float4*>(d1 + base0 + (2 * yy) * W);
        float4 a1 = *reinterpret_cast<const float4*>(d1 + base0 + (2 * yy) * W + 4);
        float4 a2 = *reinterpret_cast<const float4*>(d1 + base0 + (2 * yy + 1) * W);
        float4 a3 = *reinterpret_cast<const float4*>(d1 + base0 + (2 * yy + 1) * W + 4);
        float4 b0 = *reinterpret_cast<const float4*>(d2 + base0 + (2 * yy) * W);
        float4 b1 = *reinterpret_cast<const float4*>(d2 + base0 + (2 * yy) * W + 4);
        float4 b2 = *reinterpret_cast<const float4*>(d2 + base0 + (2 * yy + 1) * W);
        float4 b3 = *reinterpret_cast<const float4*>(d2 + base0 + (2 * yy + 1) * W + 4);
        float ra[2][8] = {{a0.x,a0.y,a0.z,a0.w,a1.x,a1.y,a1.z,a1.w},
                          {a2.x,a2.y,a2.z,a2.w,a3.x,a3.y,a3.z,a3.w}};
        float rb[2][8] = {{b0.x,b0.y,b0.z,b0.w,b1.x,b1.y,b1.z,b1.w},
                          {b2.x,b2.y,b2.z,b2.w,b3.x,b3.y,b3.z,b3.w}};
        #pragma unroll
        for (int e = 0; e < 2; ++e) {
            float o[8];
            #pragma unroll
            for (int xx = 0; xx < 8; ++xx) o[xx] = w0 * expf(-fabsf(ra[e][xx] - rb[e][xx]));
            *reinterpret_cast<float4*>(dt0 + base0 + (2 * yy + e) * W)     = make_float4(o[0], o[1], o[2], o[3]);
            *reinterpret_cast<float4*>(dt0 + base0 + (2 * yy + e) * W + 4) = make_float4(o[4], o[5], o[6], o[7]);
        }
        #pragma unroll
        for (int xx = 0; xx < 4; ++xx) {
            q1[yy][xx] = 0.25f * (ra[0][2 * xx] + ra[0][2 * xx + 1] + ra[1][2 * xx] + ra[1][2 * xx + 1]);
            q2[yy][xx] = 0.25f * (rb[0][2 * xx] + rb[0][2 * xx + 1] + rb[1][2 * xx] + rb[1][2 * xx + 1]);
        }
    }
    #pragma unroll
    for (int yy = 0; yy < 4; ++yy)
        #pragma unroll
        for (int xx = 0; xx < 4; ++xx)
            dt1[((size_t)b * 64 + ry * 4 + yy) * 96 + rx * 4 + xx] = w0 * expf(-fabsf(q1[yy][xx] - q2[yy][xx]));

    float r1[2][2], r2m[2][2];
    #pragma unroll
    for (int y = 0; y < 2; ++y)
        #pragma unroll
        for (int x = 0; x < 2; ++x) {
            r1[y][x]  = 0.25f * (q1[2 * y][2 * x] + q1[2 * y][2 * x + 1] + q1[2 * y + 1][2 * x] + q1[2 * y + 1][2 * x + 1]);
            r2m[y][x] = 0.25f * (q2[2 * y][2 * x] + q2[2 * y][2 * x + 1] + q2[2 * y + 1][2 * x] + q2[2 * y + 1][2 * x + 1]);
            dt2[((size_t)b * 32 + ry * 2 + y) * 48 + rx * 2 + x] = w0 * expf(-fabsf(r1[y][x] - r2m[y][x]));
        }
    float s1 = 0.25f * (r1[0][0] + r1[0][1] + r1[1][0] + r1[1][1]);
    float s2 = 0.25f * (r2m[0][0] + r2m[0][1] + r2m[1][0] + r2m[1][1]);
    dt3[((size_t)b * 16 + ry) * 24 + rx] = w0 * expf(-fabsf(s1 - s2));
}

// =====================================================================
extern "C" void kernel_launch(void* const* d_in, const int* in_sizes, int n_in,
                              void* d_out, int out_size, void* d_ws, size_t ws_size,
                              hipStream_t stream) {
    const float* f1 = (const float*)d_in[0];
    const float* f2 = (const float*)d_in[1];
    const float* d1 = (const float*)d_in[2];
    const float* d2 = (const float*)d_in[3];
    const float* dw = (const float*)d_in[4];
    float* out = (float*)d_out;
    float* ws  = (float*)d_ws;

    // ---------------- float workspace carve ----------------
    size_t o = 0;
    float* in1_0 = ws + o; o += NPX0;
    float* in1_1 = ws + o; o += NPX1;
    float* in1_2 = ws + o; o += NPX2;
    float* in1_3 = ws + o; o += NPX3;
    float* in2_0 = ws + o; o += NPX0;
    float* in2_1 = ws + o; o += NPX1;
    float* in2_2 = ws + o; o += NPX2;
    float* in2_3 = ws + o; o += NPX3;
    float* dt_0 = ws + o; o += NPX0;
    float* dt_1 = ws + o; o += NPX1;
    float* dt_2 = ws + o; o += NPX2;
    float* dt_3 = ws + o; o += NPX3;
    float* s1_0 = ws + o; o += (size_t)8 * NPX0;
    float* s1_1 = ws + o; o += (size_t)8 * NPX1;
    float* s1_2 = ws + o; o += (size_t)8 * NPX2;
    float* s1_3 = ws + o; o += (size_t)8 * NPX3;
    float* s2_0 = ws + o; o += (size_t)8 * NPX0;
    float* s2_1 = ws + o; o += (size_t)8 * NPX1;
    float* s2_2 = ws + o; o += (size_t)8 * NPX2;
    float* s2_3 = ws + o; o += (size_t)8 * NPX3;
    o = (o + 7) & ~(size_t)7;

    // ---------------- bf16 (ushort) workspace carve ----------------
    ushort_t* sws = (ushort_t*)(ws + o);
    const size_t L0 = (size_t)NPX0 * 256;
    const size_t L1 = (size_t)NPX1 * 256;
    const size_t L2 = (size_t)NPX2 * 256;
    const size_t L3 = (size_t)NPX3 * 256;
    const size_t FT = L0 + L1 + L2 + L3;
    ushort_t* f1n0 = sws;
    ushort_t* f1n1 = f1n0 + L0;
    ushort_t* f1n2 = f1n1 + L1;
    ushort_t* f1n3 = f1n2 + L2;
    ushort_t* f2n0 = sws + FT;
    ushort_t* f2n1 = f2n0 + L0;
    ushort_t* f2n2 = f2n1 + L1;
    ushort_t* f2n3 = f2n2 + L2;
    ushort_t* zblk = sws + 2 * FT;
    size_t need = o * 4 + (2 * FT + 256) * 2;
    if (ws_size < need) return;

    hipMemsetAsync(zblk, 0, 512, stream);

    depth_kernel<<<dim3(6), 256, 0, stream>>>(d1, d2, dw, dt_0, dt_1, dt_2, dt_3);

    PrepOut Pa = { f1n0, f1n1, f1n2, f1n3, s1_0, s1_1, s1_2, s1_3, in1_0, in1_1, in1_2, in1_3 };
    PrepOut Pb = { f2n0, f2n1, f2n2, f2n3, s2_0, s2_1, s2_2, s2_3, in2_0, in2_1, in2_2, in2_3 };

    // streaming prep: 4 waves/block, all same kc plane, contiguous stripes
    prep_stream_kernel<<<dim3(768, 2), 256, 0, stream>>>(f1, f2, Pa, Pb);
    invnorm_fin_kernel<<<dim3((2 * NPXT + 255) / 256), 256, 0, stream>>>(Pa, Pb);

    CorrLvl lv0 = { f1n0, f2n0, in1_0, in2_0, dt_0, out,           128, 192, 12, 16, NP32_0 };
    CorrLvl lv1 = { f1n1, f2n1, in1_1, in2_1, dt_1, out + 7962624,  64,  96,  6,  8, NP32_1 };
    CorrLvl lv2 = { f1n2, f2n2, in1_2, in2_2, dt_2, out + 9953280,  32,  48,  3,  4, NP32_2 };
    corr_fused_kernel<<<dim3(1008), 256, 0, stream>>>(lv0, lv1, lv2, zblk);

    corr_mfma_kernel<<<dim3(96 / 4), 256, 0, stream>>>(f1n3, f2n3, in1_3, in2_3, dt_3, out + 10450944, 16, 24, 6, 4,
                                                       (int)(2 * FT - (size_t)(f2n3 - sws)));
}

// Round 15
// 233.423 us; speedup vs baseline: 1.0739x; 1.0739x over previous
//
#include <hip/hip_runtime.h>
#include <hip/hip_bf16.h>

typedef __attribute__((ext_vector_type(8))) __bf16 bf16x8;
typedef __attribute__((ext_vector_type(4))) float f32x4;
typedef unsigned short ushort_t;
typedef unsigned int uint_t;

#define CCH 256
#define BB 4

// kc-plane strides in shorts: level npix * 32 ch
#define NP32_0 3145728   // 4*128*192*32
#define NP32_1 786432    // 4*64*96*32
#define NP32_2 196608    // 4*32*48*32
#define NP32_3 49152     // 4*16*24*32

#define NPX0 98304
#define NPX1 24576
#define NPX2 6144
#define NPX3 1536
#define NPXT (NPX0 + NPX1 + NPX2 + NPX3)   // 130560

__device__ __forceinline__ ushort_t f2b(float v) {
    __hip_bfloat16 h = __float2bfloat16(v);
    return *reinterpret_cast<ushort_t*>(&h);
}

__device__ __forceinline__ void gload16(const void* g, void* l) {
    __builtin_amdgcn_global_load_lds(
        (const __attribute__((address_space(1))) void*)g,
        (__attribute__((address_space(3))) void*)l, 16, 0, 0);
}

struct PrepOut {
    ushort_t* o0; ushort_t* o1; ushort_t* o2; ushort_t* o3;
    float* s0; float* s1; float* s2; float* s3;     // partial ssq [8][npx]
    float* n0; float* n1; float* n2; float* n3;     // invnorms
};

// =====================================================================
// prep_stream v5: r13 structure (1-wave blocks, depth-4 ring) but the
// thread owns a 1x4 patch -> ONE float4 (16B) load per channel instead
// of two float2 (8B) — the only correlate of the 3.4 TB/s prep variants.
// Pooling: L1 vertical shfl_xor(4); L2 in-thread + shfl_xor(8);
// L3 shfl_xor(1) + shfl_xor(16). Same association as reference.
// Wave region: 16 rows x 16 cols (ly = lane>>2, lx = lane&3).
// =====================================================================
__global__ __launch_bounds__(64) void prep_stream_kernel(
    const float* __restrict__ fa, const float* __restrict__ fb,
    PrepOut Pa, PrepOut Pb)
{
    const int H = 128, W = 192, HW = H * W;
    const float* fin = blockIdx.y ? fb : fa;
    PrepOut P = blockIdx.y ? Pb : Pa;

    int bid = blockIdx.x;
    int kc = bid & 7;
    int r0i = bid >> 3;
    int xc = r0i % 12;
    int ys = (r0i / 12) % 8;
    int b  = r0i / 96;

    int t = threadIdx.x;
    int ly = t >> 2, lx = t & 3;
    int row0 = ys * 16 + ly;
    int col0 = xc * 16 + 4 * lx;

    const float* base = fin + (size_t)(b * 256 + kc * 32) * HW + (size_t)row0 * W + col0;

    uint_t uu0[4][16];
    uint_t uu1[2][16], uu2[16], uu3[16];
    float sq0x = 0.f, sq0y = 0.f, sq0z = 0.f, sq0w = 0.f;
    float ssq1a = 0.f, ssq1b = 0.f, ssq2 = 0.f, ssq3 = 0.f;

    bool own1 = (ly & 1) == 0;
    bool own2 = (ly & 3) == 0;
    bool own3 = ((ly & 7) | (lx & 1)) == 0;

    // depth-4 prefetch ring (one float4 per channel)
    float4 ring[4];
    #pragma unroll
    for (int i = 0; i < 4; ++i)
        ring[i] = *reinterpret_cast<const float4*>(base + (size_t)i * HW);

    #pragma unroll
    for (int cc = 0; cc < 32; ++cc) {
        float4 v = ring[cc & 3];
        if (cc + 4 < 32)
            ring[cc & 3] = *reinterpret_cast<const float4*>(base + (size_t)(cc + 4) * HW);

        sq0x = fmaf(v.x, v.x, sq0x);
        sq0y = fmaf(v.y, v.y, sq0y);
        sq0z = fmaf(v.z, v.z, sq0z);
        sq0w = fmaf(v.w, v.w, sq0w);

        ushort_t b0 = f2b(v.x), b1 = f2b(v.y), b2 = f2b(v.z), b3 = f2b(v.w);
        if ((cc & 1) == 0) {
            uu0[0][cc >> 1] = (uint_t)b0;
            uu0[1][cc >> 1] = (uint_t)b1;
            uu0[2][cc >> 1] = (uint_t)b2;
            uu0[3][cc >> 1] = (uint_t)b3;
        } else {
            uu0[0][cc >> 1] |= ((uint_t)b0) << 16;
            uu0[1][cc >> 1] |= ((uint_t)b1) << 16;
            uu0[2][cc >> 1] |= ((uint_t)b2) << 16;
            uu0[3][cc >> 1] |= ((uint_t)b3) << 16;
        }

        // ---- L1: horizontal sums in-thread, vertical via shfl (ly pairs) ----
        float h0 = v.x + v.y;
        float h1 = v.z + v.w;
        float l1a = 0.25f * (h0 + __shfl_xor(h0, 4));
        float l1b = 0.25f * (h1 + __shfl_xor(h1, 4));
        ssq1a = fmaf(l1a, l1a, ssq1a);
        ssq1b = fmaf(l1b, l1b, ssq1b);
        if ((cc & 1) == 0) { uu1[0][cc >> 1] = (uint_t)f2b(l1a); uu1[1][cc >> 1] = (uint_t)f2b(l1b); }
        else               { uu1[0][cc >> 1] |= ((uint_t)f2b(l1a)) << 16; uu1[1][cc >> 1] |= ((uint_t)f2b(l1b)) << 16; }

        // ---- L2: horizontal in-thread, vertical shfl_xor(8) ----
        float vv = l1a + l1b;
        float l2 = 0.25f * (vv + __shfl_xor(vv, 8));
        ssq2 = fmaf(l2, l2, ssq2);
        if ((cc & 1) == 0) uu2[cc >> 1] = (uint_t)f2b(l2);
        else               uu2[cc >> 1] |= ((uint_t)f2b(l2)) << 16;

        // ---- L3: horizontal shfl_xor(1), vertical shfl_xor(16) ----
        float s = l2 + __shfl_xor(l2, 1);
        float l3 = 0.25f * (s + __shfl_xor(s, 16));
        ssq3 = fmaf(l3, l3, ssq3);
        if ((cc & 1) == 0) uu3[cc >> 1] = (uint_t)f2b(l3);
        else               uu3[cc >> 1] |= ((uint_t)f2b(l3)) << 16;
    }

    // ---- L0 stores: 4 consecutive pixels x 64B = 256B contiguous ----
    {
        size_t px0 = (size_t)(b * H + row0) * W + col0;
        #pragma unroll
        for (int i = 0; i < 4; ++i) {
            ushort_t* dst = P.o0 + (size_t)kc * NP32_0 + (px0 + i) * 32;
            *reinterpret_cast<uint4*>(dst +  0) = make_uint4(uu0[i][0],  uu0[i][1],  uu0[i][2],  uu0[i][3]);
            *reinterpret_cast<uint4*>(dst +  8) = make_uint4(uu0[i][4],  uu0[i][5],  uu0[i][6],  uu0[i][7]);
            *reinterpret_cast<uint4*>(dst + 16) = make_uint4(uu0[i][8],  uu0[i][9],  uu0[i][10], uu0[i][11]);
            *reinterpret_cast<uint4*>(dst + 24) = make_uint4(uu0[i][12], uu0[i][13], uu0[i][14], uu0[i][15]);
        }
        *reinterpret_cast<float4*>(P.s0 + (size_t)kc * NPX0 + px0) = make_float4(sq0x, sq0y, sq0z, sq0w);
    }

    // ---- L1 store (even-ly lanes own 2 adjacent L1 pixels: 128B) ----
    if (own1) {
        size_t l1pxA = (size_t)(b * 64 + ys * 8 + (ly >> 1)) * 96 + xc * 8 + 2 * lx;
        #pragma unroll
        for (int u = 0; u < 2; ++u) {
            ushort_t* dst = P.o1 + (size_t)kc * NP32_1 + (l1pxA + u) * 32;
            *reinterpret_cast<uint4*>(dst +  0) = make_uint4(uu1[u][0],  uu1[u][1],  uu1[u][2],  uu1[u][3]);
            *reinterpret_cast<uint4*>(dst +  8) = make_uint4(uu1[u][4],  uu1[u][5],  uu1[u][6],  uu1[u][7]);
            *reinterpret_cast<uint4*>(dst + 16) = make_uint4(uu1[u][8],  uu1[u][9],  uu1[u][10], uu1[u][11]);
            *reinterpret_cast<uint4*>(dst + 24) = make_uint4(uu1[u][12], uu1[u][13], uu1[u][14], uu1[u][15]);
        }
        *reinterpret_cast<float2*>(P.s1 + (size_t)kc * NPX1 + l1pxA) = make_float2(ssq1a, ssq1b);
    }

    // ---- L2 store ----
    if (own2) {
        size_t l2px = (size_t)(b * 32 + ys * 4 + (ly >> 2)) * 48 + xc * 4 + lx;
        ushort_t* dst = P.o2 + (size_t)kc * NP32_2 + l2px * 32;
        *reinterpret_cast<uint4*>(dst +  0) = make_uint4(uu2[0],  uu2[1],  uu2[2],  uu2[3]);
        *reinterpret_cast<uint4*>(dst +  8) = make_uint4(uu2[4],  uu2[5],  uu2[6],  uu2[7]);
        *reinterpret_cast<uint4*>(dst + 16) = make_uint4(uu2[8],  uu2[9],  uu2[10], uu2[11]);
        *reinterpret_cast<uint4*>(dst + 24) = make_uint4(uu2[12], uu2[13], uu2[14], uu2[15]);
        P.s2[(size_t)kc * NPX2 + l2px] = ssq2;
    }

    // ---- L3 store ----
    if (own3) {
        size_t l3px = (size_t)(b * 16 + ys * 2 + (ly >> 3)) * 24 + xc * 2 + (lx >> 1);
        ushort_t* dst = P.o3 + (size_t)kc * NP32_3 + l3px * 32;
        *reinterpret_cast<uint4*>(dst +  0) = make_uint4(uu3[0],  uu3[1],  uu3[2],  uu3[3]);
        *reinterpret_cast<uint4*>(dst +  8) = make_uint4(uu3[4],  uu3[5],  uu3[6],  uu3[7]);
        *reinterpret_cast<uint4*>(dst + 16) = make_uint4(uu3[8],  uu3[9],  uu3[10], uu3[11]);
        *reinterpret_cast<uint4*>(dst + 24) = make_uint4(uu3[12], uu3[13], uu3[14], uu3[15]);
        P.s3[(size_t)kc * NPX3 + l3px] = ssq3;
    }
}

// =====================================================================
// invnorm finalize: sum the 8 kc-partials, write 1/max(sqrt,eps)
// =====================================================================
__global__ __launch_bounds__(256) void invnorm_fin_kernel(PrepOut Pa, PrepOut Pb)
{
    int tid = blockIdx.x * 256 + threadIdx.x;
    if (tid >= 2 * NPXT) return;
    PrepOut P = (tid >= NPXT) ? Pb : Pa;
    int i = (tid >= NPXT) ? (tid - NPXT) : tid;

    const float* s; float* n; int npx, j;
    if (i < NPX0)                       { s = P.s0; n = P.n0; npx = NPX0; j = i; }
    else if (i < NPX0 + NPX1)           { s = P.s1; n = P.n1; npx = NPX1; j = i - NPX0; }
    else if (i < NPX0 + NPX1 + NPX2)    { s = P.s2; n = P.n2; npx = NPX2; j = i - NPX0 - NPX1; }
    else                                { s = P.s3; n = P.n3; npx = NPX3; j = i - NPX0 - NPX1 - NPX2; }

    float sum = 0.f;
    #pragma unroll
    for (int k = 0; k < 8; ++k) sum += s[(size_t)k * npx + j];
    n[j] = 1.f / fmaxf(sqrtf(sum), 1e-12f);
}

// =====================================================================
// corr_fused (unchanged from round 10 — proven)
// =====================================================================
struct CorrLvl {
    const ushort_t* f1n; const ushort_t* f2n;
    const float* in1; const float* in2; const float* dt;
    float* out;
    int H, W, TX, TY, npix32;
};

__global__ __launch_bounds__(256, 2) void corr_fused_kernel(
    CorrLvl Lv0, CorrLvl Lv1, CorrLvl Lv2, const ushort_t* __restrict__ zblk)
{
    __shared__ char smem[65536];
    char* As = smem;
    char* Bs = smem + 16384;

    int bid = blockIdx.x;
    CorrLvl L;
    int local;
    if (bid < 768)      { L = Lv0; local = bid; }
    else if (bid < 960) { L = Lv1; local = bid - 768; }
    else                { L = Lv2; local = bid - 960; }

    int H = L.H, W = L.W, TX = L.TX, TY = L.TY, npix32 = L.npix32;
    int cpx = (BB * TX * TY) >> 3;
    int swz = (local & 7) * cpx + (local >> 3);
    int tx = swz % TX;
    int ty = (swz / TX) % TY;
    int b  = swz / (TX * TY);
    int x0 = tx * 16, y0 = ty * 8;

    int tid = threadIdx.x;
    int w = tid >> 6, lane = tid & 63;
    int kg = lane >> 4, col = lane & 15;
    int r2 = col >> 2, c2 = col & 3;
    int sy = w >> 1, p = w & 1;
    int kgx = kg ^ c2;

    const ushort_t* srcA[2]; char* ldsA[2];
    #pragma unroll
    for (int q = 0; q < 2; ++q) {
        int row = w * 2 + q;
        int px = lane >> 2, js = lane & 3;
        int j = js ^ (px & 3);
        srcA[q] = L.f1n + ((size_t)((b * H + y0 + row) * W) + x0 + px) * 32 + j * 8;
        ldsA[q] = As + row * 1024;
    }
    const ushort_t* srcB[6]; int advB[6]; char* ldsB[6];
    #pragma unroll
    for (int q = 0; q < 6; ++q) {
        int u = (w * 6 + q) * 64 + lane;
        int row = u / 96, rem = u % 96;
        int px = rem >> 2, js = rem & 3;
        int j = js ^ (px & 3);
        int py = y0 - 4 + row, pxg = x0 - 4 + px;
        bool v = (py >= 0) && (py < H) && (pxg >= 0) && (pxg < W);
        srcB[q] = v ? (L.f2n + ((size_t)((b * H + py) * W) + pxg) * 32 + j * 8) : (zblk + j * 8);
        advB[q] = v ? npix32 : 0;
        ldsB[q] = Bs + (w * 6 + q) * 1024;
    }

    int aoff[2], boff[3][4];
    #pragma unroll
    for (int s = 0; s < 2; ++s) {
        int ly = 4 * sy + r2;
        int lx = 4 * (2 * p + s) + c2;
        aoff[s] = ((ly * 16 + lx) * 4 + kgx) * 16;
    }
    #pragma unroll
    for (int i = 0; i < 3; ++i)
        #pragma unroll
        for (int j = 0; j < 4; ++j) {
            int wy = 4 * (sy + i) + r2;
            int wx = 4 * (2 * p + j) + c2;
            boff[i][j] = ((wy * 24 + wx) * 4 + kgx) * 16;
        }

    f32x4 acc0[3][3] = {};
    f32x4 acc1[3][3] = {};

    #pragma unroll
    for (int q = 0; q < 2; ++q) { gload16(srcA[q], ldsA[q]); srcA[q] += npix32; }
    #pragma unroll
    for (int q = 0; q < 6; ++q) { gload16(srcB[q], ldsB[q]); srcB[q] += advB[q]; }

    int buf = 0;
    #pragma unroll 1
    for (int kc = 0; kc < 8; ++kc) {
        if (kc < 7) {
            int boA = (buf ^ 1) * 8192;
            int boB = (buf ^ 1) * 24576;
            #pragma unroll
            for (int q = 0; q < 2; ++q) { gload16(srcA[q], ldsA[q] + boA); srcA[q] += npix32; }
            #pragma unroll
            for (int q = 0; q < 6; ++q) { gload16(srcB[q], ldsB[q] + boB); srcB[q] += advB[q]; }
            __builtin_amdgcn_sched_barrier(0);
            asm volatile("s_waitcnt vmcnt(8)" ::: "memory");
        } else {
            __builtin_amdgcn_sched_barrier(0);
            asm volatile("s_waitcnt vmcnt(0)" ::: "memory");
        }
        __builtin_amdgcn_s_barrier();
        __builtin_amdgcn_sched_barrier(0);

        const char* Ab = As + buf * 8192;
        const char* Bb = Bs + buf * 24576;
        bf16x8 av0 = *(const bf16x8*)(Ab + aoff[0]);
        bf16x8 av1 = *(const bf16x8*)(Ab + aoff[1]);
        #pragma unroll
        for (int i = 0; i < 3; ++i) {
            #pragma unroll
            for (int j = 0; j < 4; ++j) {
                bf16x8 bv = *(const bf16x8*)(Bb + boff[i][j]);
                if (j < 3) acc0[i][j]     = __builtin_amdgcn_mfma_f32_16x16x32_bf16(av0, bv, acc0[i][j], 0, 0, 0);
                if (j > 0) acc1[i][j - 1] = __builtin_amdgcn_mfma_f32_16x16x32_bf16(av1, bv, acc1[i][j - 1], 0, 0, 0);
            }
        }
        if (kc < 7) {
            __builtin_amdgcn_sched_barrier(0);
            __builtin_amdgcn_s_barrier();
            __builtin_amdgcn_sched_barrier(0);
        }
        buf ^= 1;
    }

    float inv1v[2][4], dtv[2][4];
    #pragma unroll
    for (int s = 0; s < 2; ++s) {
        int sxs = 2 * p + s;
        #pragma unroll
        for (int rr = 0; rr < 4; ++rr) {
            int m = kg * 4 + rr;
            int iy = m >> 2, ix = m & 3;
            int pix = (b * H + y0 + 4 * sy + iy) * W + x0 + 4 * sxs + ix;
            inv1v[s][rr] = L.in1[pix];
            dtv[s][rr]   = L.dt[pix];
        }
    }
    #pragma unroll
    for (int s = 0; s < 2; ++s) {
        int sxs = 2 * p + s;
        #pragma unroll
        for (int i = 0; i < 3; ++i) {
            #pragma unroll
            for (int jj = 0; jj < 3; ++jj) {
                int wy = 4 * (sy + i) + r2;
                int wxr = 4 * (sxs + jj) + c2;
                int py = y0 - 4 + wy, px = x0 - 4 + wxr;
                bool v = (py >= 0) && (py < H) && (px >= 0) && (px < W);
                float i2 = v ? L.in2[(b * H + py) * W + px] : 0.f;
                f32x4 a = (s == 0) ? acc0[i][jj] : acc1[i][jj];
                #pragma unroll
                for (int rr = 0; rr < 4; ++rr) {
                    int m = kg * 4 + rr;
                    int iy = m >> 2, ix = m & 3;
                    int oy = iy + 8 - (4 * i + r2);
                    int ox = ix + 8 - (4 * jj + c2);
                    if (oy >= 0 && oy < 9 && ox >= 0 && ox < 9) {
                        int gy = y0 + 4 * sy + iy, gx = x0 + 4 * sxs + ix;
                        L.out[((size_t)(b * 81 + oy * 9 + ox) * H + gy) * W + gx]
                            = a[rr] * inv1v[s][rr] * i2 + dtv[s][rr];
                    }
                }
            }
        }
    }
}

// =====================================================================
// corr_mfma — L3 only (unchanged)
// =====================================================================
__global__ __launch_bounds__(256) void corr_mfma_kernel(
    const ushort_t* __restrict__ f1n, const ushort_t* __restrict__ f2n,
    const float* __restrict__ invn1, const float* __restrict__ invn2,
    const float* __restrict__ dt, float* __restrict__ out,
    int H, int W, int TX, int TY, int zoff)
{
    int wid  = threadIdx.x >> 6;
    int lane = threadIdx.x & 63;
    int tile = blockIdx.x * 4 + wid;
    int ntiles = BB * TY * TX;
    if (tile >= ntiles) return;
    int tx = tile % TX;
    int ty = (tile / TX) % TY;
    int b  = tile / (TX * TY);
    int x0 = tx * 4, y0 = ty * 4;

    int col = lane & 15;
    int kg  = lane >> 4;

    int iyA = col >> 2, ixA = col & 3;
    int a_off = (((b * H + y0 + iyA) * W) + x0 + ixA) * 32 + kg * 8;

    int b_off[9], badv[9];
    uint_t vmask = 0;
    #pragma unroll
    for (int tt = 0; tt < 9; ++tt) {
        int w = tt * 16 + col;
        int wy = w / 12, wx = w % 12;
        int py = y0 + wy - 4, px = x0 + wx - 4;
        bool v = (py >= 0) && (py < H) && (px >= 0) && (px < W);
        b_off[tt] = v ? (((b * H + py) * W + px) * 32 + kg * 8) : (zoff + kg * 8);
        badv[tt] = v ? NP32_3 : 0;
        if (v) vmask |= (1u << tt);
    }

    f32x4 acc[9] = {};
    #pragma unroll
    for (int kb = 0; kb < 8; ++kb) {
        bf16x8 av = *reinterpret_cast<const bf16x8*>(f1n + a_off + kb * NP32_3);
        #pragma unroll
        for (int tt = 0; tt < 9; ++tt) {
            bf16x8 bv = *reinterpret_cast<const bf16x8*>(f2n + b_off[tt]);
            acc[tt] = __builtin_amdgcn_mfma_f32_16x16x32_bf16(av, bv, acc[tt], 0, 0, 0);
            b_off[tt] += badv[tt];
        }
    }

    float inv1[4], dts[4];
    #pragma unroll
    for (int r = 0; r < 4; ++r) {
        int m = kg * 4 + r;
        int iy = m >> 2, ix = m & 3;
        int pix = (b * H + y0 + iy) * W + x0 + ix;
        inv1[r] = invn1[pix];
        dts[r]  = dt[pix];
    }
    #pragma unroll
    for (int tt = 0; tt < 9; ++tt) {
        int w = tt * 16 + col;
        int wy = w / 12, wx = w % 12;
        int py = y0 + wy - 4, px = x0 + wx - 4;
        float i2 = ((vmask >> tt) & 1u) ? invn2[(b * H + py) * W + px] : 0.f;
        #pragma unroll
        for (int r = 0; r < 4; ++r) {
            int m = kg * 4 + r;
            int iy = m >> 2, ix = m & 3;
            int oy = iy + 8 - wy, ox = ix + 8 - wx;
            if (oy >= 0 && oy < 9 && ox >= 0 && ox < 9) {
                int o = oy * 9 + ox;
                out[((size_t)(b * 81 + o) * H + (y0 + iy)) * W + (x0 + ix)]
                    = acc[tt][r] * inv1[r] * i2 + dts[r];
            }
        }
    }
}

// =====================================================================
// depth (unchanged)
// =====================================================================
__global__ __launch_bounds__(256) void depth_kernel(
    const float* __restrict__ d1, const float* __restrict__ d2,
    const float* __restrict__ dw,
    float* __restrict__ dt0, float* __restrict__ dt1,
    float* __restrict__ dt2, float* __restrict__ dt3)
{
    int rid = blockIdx.x * 256 + threadIdx.x;
    if (rid >= 4 * 16 * 24) return;
    int b = rid / 384, rr = rid % 384, ry = rr / 24, rx = rr % 24;
    const int H = 128, W = 192;
    float w0 = dw[0];
    size_t base0 = ((size_t)b * H + ry * 8) * W + rx * 8;

    float q1[4][4], q2[4][4];
    #pragma unroll
    for (int yy = 0; yy < 4; ++yy) {
        float4 a0 = *reinterpret_cast<const float4*>(d1 + base0 + (2 * yy) * W);
        float4 a1 = *reinterpret_cast<const float4*>(d1 + base0 + (2 * yy) * W + 4);
        float4 a2 = *reinterpret_cast<const float4*>(d1 + base0 + (2 * yy + 1) * W);
        float4 a3 = *reinterpret_cast<const float4*>(d1 + base0 + (2 * yy + 1) * W + 4);
        float4 b0 = *reinterpret_cast<const float4*>(d2 + base0 + (2 * yy) * W);
        float4 b1 = *reinterpret_cast<const float4*>(d2 + base0 + (2 * yy) * W + 4);
        float4 b2 = *reinterpret_cast<const float4*>(d2 + base0 + (2 * yy + 1) * W);
        float4 b3 = *reinterpret_cast<const float4*>(d2 + base0 + (2 * yy + 1) * W + 4);
        float ra[2][8] = {{a0.x,a0.y,a0.z,a0.w,a1.x,a1.y,a1.z,a1.w},
                          {a2.x,a2.y,a2.z,a2.w,a3.x,a3.y,a3.z,a3.w}};
        float rb[2][8] = {{b0.x,b0.y,b0.z,b0.w,b1.x,b1.y,b1.z,b1.w},
                          {b2.x,b2.y,b2.z,b2.w,b3.x,b3.y,b3.z,b3.w}};
        #pragma unroll
        for (int e = 0; e < 2; ++e) {
            float o[8];
            #pragma unroll
            for (int xx = 0; xx < 8; ++xx) o[xx] = w0 * expf(-fabsf(ra[e][xx] - rb[e][xx]));
            *reinterpret_cast<float4*>(dt0 + base0 + (2 * yy + e) * W)     = make_float4(o[0], o[1], o[2], o[3]);
            *reinterpret_cast<float4*>(dt0 + base0 + (2 * yy + e) * W + 4) = make_float4(o[4], o[5], o[6], o[7]);
        }
        #pragma unroll
        for (int xx = 0; xx < 4; ++xx) {
            q1[yy][xx] = 0.25f * (ra[0][2 * xx] + ra[0][2 * xx + 1] + ra[1][2 * xx] + ra[1][2 * xx + 1]);
            q2[yy][xx] = 0.25f * (rb[0][2 * xx] + rb[0][2 * xx + 1] + rb[1][2 * xx] + rb[1][2 * xx + 1]);
        }
    }
    #pragma unroll
    for (int yy = 0; yy < 4; ++yy)
        #pragma unroll
        for (int xx = 0; xx < 4; ++xx)
            dt1[((size_t)b * 64 + ry * 4 + yy) * 96 + rx * 4 + xx] = w0 * expf(-fabsf(q1[yy][xx] - q2[yy][xx]));

    float r1[2][2], r2m[2][2];
    #pragma unroll
    for (int y = 0; y < 2; ++y)
        #pragma unroll
        for (int x = 0; x < 2; ++x) {
            r1[y][x]  = 0.25f * (q1[2 * y][2 * x] + q1[2 * y][2 * x + 1] + q1[2 * y + 1][2 * x] + q1[2 * y + 1][2 * x + 1]);
            r2m[y][x] = 0.25f * (q2[2 * y][2 * x] + q2[2 * y][2 * x + 1] + q2[2 * y + 1][2 * x] + q2[2 * y + 1][2 * x + 1]);
            dt2[((size_t)b * 32 + ry * 2 + y) * 48 + rx * 2 + x] = w0 * expf(-fabsf(r1[y][x] - r2m[y][x]));
        }
    float s1 = 0.25f * (r1[0][0] + r1[0][1] + r1[1][0] + r1[1][1]);
    float s2 = 0.25f * (r2m[0][0] + r2m[0][1] + r2m[1][0] + r2m[1][1]);
    dt3[((size_t)b * 16 + ry) * 24 + rx] = w0 * expf(-fabsf(s1 - s2));
}

// =====================================================================
extern "C" void kernel_launch(void* const* d_in, const int* in_sizes, int n_in,
                              void* d_out, int out_size, void* d_ws, size_t ws_size,
                              hipStream_t stream) {
    const float* f1 = (const float*)d_in[0];
    const float* f2 = (const float*)d_in[1];
    const float* d1 = (const float*)d_in[2];
    const float* d2 = (const float*)d_in[3];
    const float* dw = (const float*)d_in[4];
    float* out = (float*)d_out;
    float* ws  = (float*)d_ws;

    // ---------------- float workspace carve ----------------
    size_t o = 0;
    float* in1_0 = ws + o; o += NPX0;
    float* in1_1 = ws + o; o += NPX1;
    float* in1_2 = ws + o; o += NPX2;
    float* in1_3 = ws + o; o += NPX3;
    float* in2_0 = ws + o; o += NPX0;
    float* in2_1 = ws + o; o += NPX1;
    float* in2_2 = ws + o; o += NPX2;
    float* in2_3 = ws + o; o += NPX3;
    float* dt_0 = ws + o; o += NPX0;
    float* dt_1 = ws + o; o += NPX1;
    float* dt_2 = ws + o; o += NPX2;
    float* dt_3 = ws + o; o += NPX3;
    float* s1_0 = ws + o; o += (size_t)8 * NPX0;
    float* s1_1 = ws + o; o += (size_t)8 * NPX1;
    float* s1_2 = ws + o; o += (size_t)8 * NPX2;
    float* s1_3 = ws + o; o += (size_t)8 * NPX3;
    float* s2_0 = ws + o; o += (size_t)8 * NPX0;
    float* s2_1 = ws + o; o += (size_t)8 * NPX1;
    float* s2_2 = ws + o; o += (size_t)8 * NPX2;
    float* s2_3 = ws + o; o += (size_t)8 * NPX3;
    o = (o + 7) & ~(size_t)7;

    // ---------------- bf16 (ushort) workspace carve ----------------
    ushort_t* sws = (ushort_t*)(ws + o);
    const size_t L0 = (size_t)NPX0 * 256;
    const size_t L1 = (size_t)NPX1 * 256;
    const size_t L2 = (size_t)NPX2 * 256;
    const size_t L3 = (size_t)NPX3 * 256;
    const size_t FT = L0 + L1 + L2 + L3;
    ushort_t* f1n0 = sws;
    ushort_t* f1n1 = f1n0 + L0;
    ushort_t* f1n2 = f1n1 + L1;
    ushort_t* f1n3 = f1n2 + L2;
    ushort_t* f2n0 = sws + FT;
    ushort_t* f2n1 = f2n0 + L0;
    ushort_t* f2n2 = f2n1 + L1;
    ushort_t* f2n3 = f2n2 + L2;
    ushort_t* zblk = sws + 2 * FT;
    size_t need = o * 4 + (2 * FT + 256) * 2;
    if (ws_size < need) return;

    hipMemsetAsync(zblk, 0, 512, stream);

    depth_kernel<<<dim3(6), 256, 0, stream>>>(d1, d2, dw, dt_0, dt_1, dt_2, dt_3);

    PrepOut Pa = { f1n0, f1n1, f1n2, f1n3, s1_0, s1_1, s1_2, s1_3, in1_0, in1_1, in1_2, in1_3 };
    PrepOut Pb = { f2n0, f2n1, f2n2, f2n3, s2_0, s2_1, s2_2, s2_3, in2_0, in2_1, in2_2, in2_3 };

    // streaming prep: 1-wave blocks (proven best), 16B float4 loads
    prep_stream_kernel<<<dim3(3072, 2), 64, 0, stream>>>(f1, f2, Pa, Pb);
    invnorm_fin_kernel<<<dim3((2 * NPXT + 255) / 256), 256, 0, stream>>>(Pa, Pb);

    CorrLvl lv0 = { f1n0, f2n0, in1_0, in2_0, dt_0, out,           128, 192, 12, 16, NP32_0 };
    CorrLvl lv1 = { f1n1, f2n1, in1_1, in2_1, dt_1, out + 7962624,  64,  96,  6,  8, NP32_1 };
    CorrLvl lv2 = { f1n2, f2n2, in1_2, in2_2, dt_2, out + 9953280,  32,  48,  3,  4, NP32_2 };
    corr_fused_kernel<<<dim3(1008), 256, 0, stream>>>(lv0, lv1, lv2, zblk);

    corr_mfma_kernel<<<dim3(96 / 4), 256, 0, stream>>>(f1n3, f2n3, in1_3, in2_3, dt_3, out + 10450944, 16, 24, 6, 4,
                                                       (int)(2 * FT - (size_t)(f2n3 - sws)));
}